// Round 2
// baseline (592.806 us; speedup 1.0000x reference)
//
#include <hip/hip_runtime.h>
#include <hip/hip_bf16.h>
#include <type_traits>

typedef __attribute__((ext_vector_type(8))) short short8;
typedef __attribute__((ext_vector_type(4))) float f32x4;

__device__ __forceinline__ unsigned short f2bf(float f) {
    union { float f; unsigned int u; } v; v.f = f;
    unsigned int r = v.u + 0x7FFFu + ((v.u >> 16) & 1u);
    return (unsigned short)(r >> 16);
}
__device__ __forceinline__ float bf2f(unsigned short u) {
    union { unsigned int u; float f; } v; v.u = ((unsigned int)u) << 16;
    return v.f;
}

// ---------------------------------------------------------------------------
// C[r, n] = sum_k A[r,k] * Bt[n,k]   (A fp32; Bt fp32 or bf16; C bf16)
// 128x128 tile, BK=32, 4 waves, each wave 64x64 via 4x4 MFMA 16x16x32 bf16.
// ---------------------------------------------------------------------------
template <typename BT>
__global__ __launch_bounds__(256) void gemm_bt_kernel(
    const float* __restrict__ A, const BT* __restrict__ Bt,
    unsigned short* __restrict__ C, int MA, int NB, int K)
{
    __shared__ unsigned short As[128 * 40];   // pad 32 -> 40 (80B rows, 16B-aligned)
    __shared__ unsigned short Bs[128 * 40];

    const int tid  = threadIdx.x;
    const int m0   = blockIdx.y * 128;
    const int n0   = blockIdx.x * 128;

    const int srow = tid >> 1;          // 0..127
    const int sk   = (tid & 1) * 16;    // 0 or 16

    const int lane = tid & 63;
    const int wave = tid >> 6;
    const int wm   = (wave & 1) * 64;
    const int wn   = (wave >> 1) * 64;
    const int fm   = lane & 15;
    const int quad = lane >> 4;

    f32x4 acc[4][4];
#pragma unroll
    for (int i = 0; i < 4; ++i)
#pragma unroll
        for (int j = 0; j < 4; ++j) acc[i][j] = (f32x4){0.f, 0.f, 0.f, 0.f};

    const float* aptr = A + (size_t)(m0 + srow) * K + sk;

    for (int k0 = 0; k0 < K; k0 += 32) {
        // ---- stage A tile (fp32 -> bf16) ----
        {
            const float4* s = (const float4*)(aptr + k0);
            float4 v0 = s[0], v1 = s[1], v2 = s[2], v3 = s[3];
            short8 p0, p1;
            p0[0] = (short)f2bf(v0.x); p0[1] = (short)f2bf(v0.y);
            p0[2] = (short)f2bf(v0.z); p0[3] = (short)f2bf(v0.w);
            p0[4] = (short)f2bf(v1.x); p0[5] = (short)f2bf(v1.y);
            p0[6] = (short)f2bf(v1.z); p0[7] = (short)f2bf(v1.w);
            p1[0] = (short)f2bf(v2.x); p1[1] = (short)f2bf(v2.y);
            p1[2] = (short)f2bf(v2.z); p1[3] = (short)f2bf(v2.w);
            p1[4] = (short)f2bf(v3.x); p1[5] = (short)f2bf(v3.y);
            p1[6] = (short)f2bf(v3.z); p1[7] = (short)f2bf(v3.w);
            *(short8*)&As[srow * 40 + sk]     = p0;
            *(short8*)&As[srow * 40 + sk + 8] = p1;
        }
        // ---- stage B tile ----
        if constexpr (std::is_same<BT, float>::value) {
            const float4* s = (const float4*)(Bt + (size_t)(n0 + srow) * K + k0 + sk);
            float4 v0 = s[0], v1 = s[1], v2 = s[2], v3 = s[3];
            short8 p0, p1;
            p0[0] = (short)f2bf(v0.x); p0[1] = (short)f2bf(v0.y);
            p0[2] = (short)f2bf(v0.z); p0[3] = (short)f2bf(v0.w);
            p0[4] = (short)f2bf(v1.x); p0[5] = (short)f2bf(v1.y);
            p0[6] = (short)f2bf(v1.z); p0[7] = (short)f2bf(v1.w);
            p1[0] = (short)f2bf(v2.x); p1[1] = (short)f2bf(v2.y);
            p1[2] = (short)f2bf(v2.z); p1[3] = (short)f2bf(v2.w);
            p1[4] = (short)f2bf(v3.x); p1[5] = (short)f2bf(v3.y);
            p1[6] = (short)f2bf(v3.z); p1[7] = (short)f2bf(v3.w);
            *(short8*)&Bs[srow * 40 + sk]     = p0;
            *(short8*)&Bs[srow * 40 + sk + 8] = p1;
        } else {
            const short8* s = (const short8*)(Bt + (size_t)(n0 + srow) * K + k0 + sk);
            short8 u0 = s[0], u1 = s[1];
            *(short8*)&Bs[srow * 40 + sk]     = u0;
            *(short8*)&Bs[srow * 40 + sk + 8] = u1;
        }
        __syncthreads();

        // ---- MFMA ----
        short8 af[4], bfr[4];
#pragma unroll
        for (int i = 0; i < 4; ++i)
            af[i] = *(const short8*)&As[(wm + i * 16 + fm) * 40 + quad * 8];
#pragma unroll
        for (int j = 0; j < 4; ++j)
            bfr[j] = *(const short8*)&Bs[(wn + j * 16 + fm) * 40 + quad * 8];
#pragma unroll
        for (int i = 0; i < 4; ++i)
#pragma unroll
            for (int j = 0; j < 4; ++j)
                acc[i][j] = __builtin_amdgcn_mfma_f32_16x16x32_bf16(
                    af[i], bfr[j], acc[i][j], 0, 0, 0);
        __syncthreads();
    }

    // epilogue: D layout col=lane&15, row=quad*4+reg  [m89-verified]
#pragma unroll
    for (int i = 0; i < 4; ++i)
#pragma unroll
        for (int j = 0; j < 4; ++j)
#pragma unroll
            for (int r = 0; r < 4; ++r) {
                const int row = m0 + wm + i * 16 + quad * 4 + r;
                const int col = n0 + wn + j * 16 + fm;
                C[(size_t)row * NB + col] = f2bf(acc[i][j][r]);
            }
}

// ---------------------------------------------------------------------------
// G[b,i,j] = sum_d T[i*Bsz+b, d] * F[j*Bsz+b, d]   (T bf16, F fp32)
// one block per batch; stage both 8x1024 row-sets in LDS as fp32.
// ---------------------------------------------------------------------------
__global__ __launch_bounds__(256) void gram_kernel(
    const unsigned short* __restrict__ T, const float* __restrict__ F,
    float* __restrict__ G, int Bsz)
{
    __shared__ float Tsh[8 * 1024];
    __shared__ float Fsh[8 * 1024];
    const int b = blockIdx.x;
    const int tid = threadIdx.x;
    {
        const int i = tid >> 5, seg = tid & 31;
        const ushort4* s4 = (const ushort4*)(T + ((size_t)i * Bsz + b) * 1024 + seg * 32);
        float* dst = Tsh + i * 1024 + seg * 32;
#pragma unroll
        for (int c = 0; c < 8; ++c) {
            ushort4 u = s4[c];
            dst[c * 4 + 0] = bf2f(u.x); dst[c * 4 + 1] = bf2f(u.y);
            dst[c * 4 + 2] = bf2f(u.z); dst[c * 4 + 3] = bf2f(u.w);
        }
        const float4* f4 = (const float4*)(F + ((size_t)i * Bsz + b) * 1024 + seg * 32);
        float4* fd = (float4*)(Fsh + i * 1024 + seg * 32);
#pragma unroll
        for (int c = 0; c < 8; ++c) fd[c] = f4[c];
    }
    __syncthreads();

    const int lane = tid & 63, wave = tid >> 6;
    const float4* T4 = (const float4*)Tsh;
    const float4* F4 = (const float4*)Fsh;
#pragma unroll
    for (int pp = 0; pp < 16; ++pp) {
        const int i = wave * 2 + (pp >> 3);
        const int j = pp & 7;
        float s = 0.f;
#pragma unroll
        for (int c = 0; c < 4; ++c) {
            float4 tv = T4[i * 256 + lane + 64 * c];
            float4 fv = F4[j * 256 + lane + 64 * c];
            s += tv.x * fv.x + tv.y * fv.y + tv.z * fv.z + tv.w * fv.w;
        }
#pragma unroll
        for (int m2 = 32; m2 >= 1; m2 >>= 1) s += __shfl_xor(s, m2, 64);
        if (lane == 0) G[((size_t)b << 6) + i * 8 + j] = s;
    }
}

// ---------------------------------------------------------------------------
// softmax / attention maps / pooled weights.  one wave per batch.
// ---------------------------------------------------------------------------
// np.triu_indices(8,1) pair lists. NOTE: exactly 28 entries each — R1 bug was
// a missing trailing 7 in c_PJ (pair 27 = (6,7) silently became (6,0)).
__device__ __constant__ int c_PI[28] = {0,0,0,0,0,0,0, 1,1,1,1,1,1, 2,2,2,2,2, 3,3,3,3, 4,4,4, 5,5, 6};
__device__ __constant__ int c_PJ[28] = {1,2,3,4,5,6,7, 2,3,4,5,6,7, 3,4,5,6,7, 4,5,6,7, 5,6,7, 6,7, 7};
__device__ __constant__ int c_POF[8][7] = {
    {0,1,2,3,4,5,6},      {0,7,8,9,10,11,12},   {1,7,13,14,15,16,17}, {2,8,13,18,19,20,21},
    {3,9,14,18,22,23,24}, {4,10,15,19,22,25,26},{5,11,16,20,23,25,27},{6,12,17,21,24,26,27}};

__global__ __launch_bounds__(256) void att_kernel(
    const float* __restrict__ G1, const float* __restrict__ G2,
    float* __restrict__ attR, float* __restrict__ attP,
    float* __restrict__ wR, float* __restrict__ wP, int Bsz)
{
    const int lane = threadIdx.x & 63;
    const int wave = threadIdx.x >> 6;
    const int b = blockIdx.x * 4 + wave;

    int ka, kb;
    if (lane < 8)       { ka = lane;            kb = -1; }
    else if (lane < 36) { ka = c_PI[lane - 8];  kb = c_PJ[lane - 8]; }
    else                { ka = 0;               kb = -1; }
    const bool act = lane < 36;
    const float scale = 0.03125f;   // 1/sqrt(1024)

    for (int side = 0; side < 2; ++side) {
        const float* G = side ? G2 : G1;
        float g = G[((size_t)b << 6) + lane];   // lane l holds G[b][l/8][l%8]
        float attacc = 0.f;
        for (int q = 0; q < 36; ++q) {
            int qa, qb;
            if (q < 8) { qa = q;           qb = -1; }
            else       { qa = c_PI[q - 8]; qb = c_PJ[q - 8]; }
            const int kb2 = (kb < 0) ? ka : kb;
            float s  = __shfl(g, qa * 8 + ka, 64);
            float s2 = __shfl(g, qa * 8 + kb2, 64);
            s += (kb >= 0) ? s2 : 0.f;
            if (qb >= 0) {
                float s3 = __shfl(g, qb * 8 + ka, 64);
                float s4 = __shfl(g, qb * 8 + kb2, 64);
                s += s3 + ((kb >= 0) ? s4 : 0.f);
            }
            s = act ? s * scale : -__builtin_inff();
            float mx = s;
#pragma unroll
            for (int m2 = 32; m2 >= 1; m2 >>= 1) mx = fmaxf(mx, __shfl_xor(mx, m2, 64));
            float e = act ? __expf(s - mx) : 0.f;
            float sum = e;
#pragma unroll
            for (int m2 = 32; m2 >= 1; m2 >>= 1) sum += __shfl_xor(sum, m2, 64);
            attacc += e / sum;
        }
        const float att = attacc * (1.f / 36.f);
        if (act) (side ? attP : attR)[(size_t)b * 36 + lane] = att;

        // pooled weights: w[m] = att[m] + sum over pairs containing m
        const int m = lane & 7;
        float w = __shfl(att, m, 64);
#pragma unroll
        for (int t = 0; t < 7; ++t) w += __shfl(att, 8 + c_POF[m][t], 64);
        if (lane < 8) (side ? wP : wR)[(size_t)b * 8 + m] = w;
    }
}

// ---------------------------------------------------------------------------
// reaction pooling + prediction head.  one block per batch.
// ---------------------------------------------------------------------------
__global__ __launch_bounds__(256) void pool_kernel(
    const float* __restrict__ r, const float* __restrict__ rn,
    const float* __restrict__ p, const float* __restrict__ pn,
    const float* __restrict__ wR, const float* __restrict__ wP,
    const float* __restrict__ Wpred, const float* __restrict__ bpred,
    float* __restrict__ out, int Bsz)
{
    const int b = blockIdx.x;
    const int tid = threadIdx.x;          // float4 index over D: d = tid*4
    float ax = 0.f, ay = 0.f, az = 0.f, aw = 0.f;
#pragma unroll
    for (int m = 0; m < 8; ++m) {
        const float w = wR[b * 8 + m];
        const size_t off = ((size_t)m * Bsz + b) * 256 + tid;
        float4 rv = ((const float4*)r)[off];
        float4 rnv = ((const float4*)rn)[off];
        ax += w * (rv.x + rnv.x); ay += w * (rv.y + rnv.y);
        az += w * (rv.z + rnv.z); aw += w * (rv.w + rnv.w);
    }
#pragma unroll
    for (int m = 0; m < 8; ++m) {
        const float w = wP[b * 8 + m];
        const size_t off = ((size_t)m * Bsz + b) * 256 + tid;
        float4 pv = ((const float4*)p)[off];
        float4 pnv = ((const float4*)pn)[off];
        ax -= w * (pv.x + pnv.x); ay -= w * (pv.y + pnv.y);
        az -= w * (pv.z + pnv.z); aw -= w * (pv.w + pnv.w);
    }
    float o[4];
#pragma unroll
    for (int oo = 0; oo < 4; ++oo) {
        float4 w = ((const float4*)Wpred)[oo * 256 + tid];
        o[oo] = ax * w.x + ay * w.y + az * w.z + aw * w.w;
    }
    const int lane = tid & 63, wave = tid >> 6;
#pragma unroll
    for (int oo = 0; oo < 4; ++oo)
#pragma unroll
        for (int m2 = 32; m2 >= 1; m2 >>= 1) o[oo] += __shfl_xor(o[oo], m2, 64);
    __shared__ float sm[4][4];
    if (lane == 0) { sm[wave][0] = o[0]; sm[wave][1] = o[1]; sm[wave][2] = o[2]; sm[wave][3] = o[3]; }
    __syncthreads();
    if (tid < 4)
        out[(size_t)b * 4 + tid] = sm[0][tid] + sm[1][tid] + sm[2][tid] + sm[3][tid] + bpred[tid];
}

// ---------------------------------------------------------------------------
extern "C" void kernel_launch(void* const* d_in, const int* in_sizes, int n_in,
                              void* d_out, int out_size, void* d_ws, size_t ws_size,
                              hipStream_t stream)
{
    const float* r     = (const float*)d_in[0];
    const float* p     = (const float*)d_in[1];
    const float* rn    = (const float*)d_in[2];
    const float* pn    = (const float*)d_in[3];
    const float* Wq    = (const float*)d_in[4];
    const float* Wk    = (const float*)d_in[5];
    const float* Wpred = (const float*)d_in[6];
    const float* bpred = (const float*)d_in[7];

    const int Bsz = 2048, MROW = 8 * 2048;

    char* ws = (char*)d_ws;
    unsigned short* Wct = (unsigned short*)ws;                        // 2 MB  (Wc^T, bf16 [n,k])
    unsigned short* T   = (unsigned short*)(ws + (size_t)(2  << 20)); // 32 MB (proj, bf16, reused)
    float* G1 = (float*)(ws + (size_t)(34 << 20));                    // 512 KB
    float* G2 = G1 + (size_t)Bsz * 64;                                // 512 KB
    float* wRp = G2 + (size_t)Bsz * 64;                               // 64 KB
    float* wPp = wRp + (size_t)Bsz * 8;                               // 64 KB

    float* out  = (float*)d_out;
    float* attR = out + (size_t)Bsz * 4;
    float* attP = attR + (size_t)Bsz * 36;

    // 1. Wct[n,k] = sum_e Wk[n,e] * Wq[k,e]   (= (Wq Wk^T)^T, i.e. Wc in [n,k])
    gemm_bt_kernel<float><<<dim3(8, 8), 256, 0, stream>>>(Wk, Wq, Wct, 1024, 1024, 1024);
    // 2. T = p @ Wc ; 3. G1[b] = T_p[b] r[b]^T
    gemm_bt_kernel<unsigned short><<<dim3(8, 128), 256, 0, stream>>>(p, Wct, T, MROW, 1024, 1024);
    gram_kernel<<<Bsz, 256, 0, stream>>>(T, r, G1, Bsz);
    // 4. T = r @ Wc ; 5. G2[b] = T_r[b] p[b]^T
    gemm_bt_kernel<unsigned short><<<dim3(8, 128), 256, 0, stream>>>(r, Wct, T, MROW, 1024, 1024);
    gram_kernel<<<Bsz, 256, 0, stream>>>(T, p, G2, Bsz);
    // 6. softmax -> att maps + pooled weights
    att_kernel<<<Bsz / 4, 256, 0, stream>>>(G1, G2, attR, attP, wRp, wPp, Bsz);
    // 7. pooling + head
    pool_kernel<<<Bsz, 256, 0, stream>>>(r, rn, p, pn, wRp, wPp, Wpred, bpred, out, Bsz);
}

// Round 3
// 464.854 us; speedup vs baseline: 1.2753x; 1.2753x over previous
//
#include <hip/hip_runtime.h>
#include <hip/hip_bf16.h>
#include <type_traits>

typedef __attribute__((ext_vector_type(8))) short short8;
typedef __attribute__((ext_vector_type(4))) float f32x4;

__device__ __forceinline__ unsigned short f2bf(float f) {
    union { float f; unsigned int u; } v; v.f = f;
    unsigned int r = v.u + 0x7FFFu + ((v.u >> 16) & 1u);
    return (unsigned short)(r >> 16);
}
__device__ __forceinline__ float bf2f(unsigned short u) {
    union { unsigned int u; float f; } v; v.u = ((unsigned int)u) << 16;
    return v.f;
}

// async global->LDS, 16B per lane (m97 recipe). LDS dest must be lane-linear.
__device__ __forceinline__ void gl_lds16(const unsigned short* g, unsigned short* l) {
    __builtin_amdgcn_global_load_lds(
        (const __attribute__((address_space(1))) void*)g,
        (__attribute__((address_space(3))) void*)l, 16, 0, 0);
}

// ===========================================================================
// FAST PATH
// ===========================================================================

// ---- fp32 -> bf16 convert, 8 elems/thread --------------------------------
__global__ __launch_bounds__(256) void cvt_kernel(
    const float* __restrict__ src, unsigned short* __restrict__ dst, int n8)
{
    const int idx = blockIdx.x * 256 + threadIdx.x;
    if (idx >= n8) return;
    const float4* s = (const float4*)src + (size_t)idx * 2;
    float4 v0 = s[0], v1 = s[1];
    short8 o;
    o[0] = (short)f2bf(v0.x); o[1] = (short)f2bf(v0.y);
    o[2] = (short)f2bf(v0.z); o[3] = (short)f2bf(v0.w);
    o[4] = (short)f2bf(v1.x); o[5] = (short)f2bf(v1.y);
    o[6] = (short)f2bf(v1.z); o[7] = (short)f2bf(v1.w);
    ((short8*)dst)[idx] = o;
}

// ---- m97-style bf16 GEMM: C[m,n] = sum_k A[m,k]*Bt[n,k], all bf16 --------
// 128x128 tile, BK=32, unpadded LDS (global_load_lds requires lane-linear).
// grid.x = m-tile (so the 8 n-blocks of a stripe share an XCD: linear%8 = x%8)
__global__ __launch_bounds__(256) void gemm_bf16_kernel(
    const unsigned short* __restrict__ A, const unsigned short* __restrict__ Bt,
    unsigned short* __restrict__ C, int MA, int NB, int K)
{
    __shared__ unsigned short As[128 * 32];   // 8 KB, 64B rows, no pad
    __shared__ unsigned short Bs[128 * 32];

    const int tid = threadIdx.x;
    const int m0 = blockIdx.x * 128;
    const int n0 = blockIdx.y * 128;

    const int lane = tid & 63, wave = tid >> 6;
    const int wm = (wave & 1) * 64, wn = (wave >> 1) * 64;
    const int fm = lane & 15, quad = lane >> 4;

    // staging map: slot s = issue*256 + tid covers ushorts [s*8, s*8+8)
    // row = s/4 (issue0: 0..63, issue1: 64..127), col = (s%4)*8
    const int srow = tid >> 2;
    const int scol = (tid & 3) * 8;

    f32x4 acc[4][4];
#pragma unroll
    for (int i = 0; i < 4; ++i)
#pragma unroll
        for (int j = 0; j < 4; ++j) acc[i][j] = (f32x4){0.f, 0.f, 0.f, 0.f};

    const unsigned short* a0 = A + (size_t)(m0 + srow) * K + scol;
    const unsigned short* a1 = a0 + (size_t)64 * K;
    const unsigned short* b0 = Bt + (size_t)(n0 + srow) * K + scol;
    const unsigned short* b1 = b0 + (size_t)64 * K;
    unsigned short* lA0 = As + (size_t)tid * 8;
    unsigned short* lA1 = As + (size_t)(256 + tid) * 8;
    unsigned short* lB0 = Bs + (size_t)tid * 8;
    unsigned short* lB1 = Bs + (size_t)(256 + tid) * 8;

    for (int k0 = 0; k0 < K; k0 += 32) {
        gl_lds16(a0 + k0, lA0);
        gl_lds16(a1 + k0, lA1);
        gl_lds16(b0 + k0, lB0);
        gl_lds16(b1 + k0, lB1);
        __syncthreads();          // drains vmcnt (compiler emits full waitcnt)

        short8 af[4], bfr[4];
#pragma unroll
        for (int i = 0; i < 4; ++i)
            af[i] = *(const short8*)&As[(wm + i * 16 + fm) * 32 + quad * 8];
#pragma unroll
        for (int j = 0; j < 4; ++j)
            bfr[j] = *(const short8*)&Bs[(wn + j * 16 + fm) * 32 + quad * 8];
#pragma unroll
        for (int i = 0; i < 4; ++i)
#pragma unroll
            for (int j = 0; j < 4; ++j)
                acc[i][j] = __builtin_amdgcn_mfma_f32_16x16x32_bf16(
                    af[i], bfr[j], acc[i][j], 0, 0, 0);
        __syncthreads();
    }

    // D layout: col=lane&15, row=quad*4+reg [m89]
#pragma unroll
    for (int i = 0; i < 4; ++i)
#pragma unroll
        for (int j = 0; j < 4; ++j)
#pragma unroll
            for (int r = 0; r < 4; ++r) {
                const int row = m0 + wm + i * 16 + quad * 4 + r;
                const int col = n0 + wn + j * 16 + fm;
                C[(size_t)row * NB + col] = f2bf(acc[i][j][r]);
            }
}

// ---- MFMA gram: G[b,i,j] = sum_d T[i*2048+b,d] * F[j*2048+b,d] -----------
// one wave = 2 batches; A rows = 16 (T: 8 mol x 2 batches), B rows likewise.
// Diagonal 8x8 blocks of the 16x16 D are the two Grams.
__global__ __launch_bounds__(256) void gram_mfma_kernel(
    const unsigned short* __restrict__ T, const unsigned short* __restrict__ F,
    float* __restrict__ G)
{
    const int lane = threadIdx.x & 63, wave = threadIdx.x >> 6;
    const int b = blockIdx.x * 8 + wave * 2;          // batches b, b+1
    const int fm = lane & 15, quad = lane >> 4;

    const size_t row = (size_t)(fm & 7) * 2048 + (size_t)b + (fm >> 3);
    const unsigned short* tp = T + row * 1024 + quad * 8;
    const unsigned short* fp = F + row * 1024 + quad * 8;

    f32x4 acc = (f32x4){0.f, 0.f, 0.f, 0.f};
#pragma unroll 4
    for (int k0 = 0; k0 < 1024; k0 += 32) {
        short8 a = *(const short8*)(tp + k0);
        short8 bb = *(const short8*)(fp + k0);
        acc = __builtin_amdgcn_mfma_f32_16x16x32_bf16(a, bb, acc, 0, 0, 0);
    }
    // valid when batch-half of row (quad>>1) == batch-half of col (fm>>3)
    if ((quad >> 1) == (fm >> 3)) {
        const int bb_ = b + (fm >> 3);
        const int j = fm & 7;
#pragma unroll
        for (int r = 0; r < 4; ++r) {
            const int m = ((quad * 4 + r) & 7);
            G[(size_t)bb_ * 64 + m * 8 + j] = acc[r];
        }
    }
}

// ---- softmax / att maps / pooled weights (unchanged) ---------------------
__device__ __constant__ int c_PI[28] = {0,0,0,0,0,0,0, 1,1,1,1,1,1, 2,2,2,2,2, 3,3,3,3, 4,4,4, 5,5, 6};
__device__ __constant__ int c_PJ[28] = {1,2,3,4,5,6,7, 2,3,4,5,6,7, 3,4,5,6,7, 4,5,6,7, 5,6,7, 6,7, 7};
__device__ __constant__ int c_POF[8][7] = {
    {0,1,2,3,4,5,6},      {0,7,8,9,10,11,12},   {1,7,13,14,15,16,17}, {2,8,13,18,19,20,21},
    {3,9,14,18,22,23,24}, {4,10,15,19,22,25,26},{5,11,16,20,23,25,27},{6,12,17,21,24,26,27}};

__global__ __launch_bounds__(256) void att_kernel(
    const float* __restrict__ G1, const float* __restrict__ G2,
    float* __restrict__ attR, float* __restrict__ attP,
    float* __restrict__ wR, float* __restrict__ wP, int Bsz)
{
    const int lane = threadIdx.x & 63;
    const int wave = threadIdx.x >> 6;
    const int b = blockIdx.x * 4 + wave;

    int ka, kb;
    if (lane < 8)       { ka = lane;            kb = -1; }
    else if (lane < 36) { ka = c_PI[lane - 8];  kb = c_PJ[lane - 8]; }
    else                { ka = 0;               kb = -1; }
    const bool act = lane < 36;
    const float scale = 0.03125f;

    for (int side = 0; side < 2; ++side) {
        const float* G = side ? G2 : G1;
        float g = G[((size_t)b << 6) + lane];
        float attacc = 0.f;
        for (int q = 0; q < 36; ++q) {
            int qa, qb;
            if (q < 8) { qa = q;           qb = -1; }
            else       { qa = c_PI[q - 8]; qb = c_PJ[q - 8]; }
            const int kb2 = (kb < 0) ? ka : kb;
            float s  = __shfl(g, qa * 8 + ka, 64);
            float s2 = __shfl(g, qa * 8 + kb2, 64);
            s += (kb >= 0) ? s2 : 0.f;
            if (qb >= 0) {
                float s3 = __shfl(g, qb * 8 + ka, 64);
                float s4 = __shfl(g, qb * 8 + kb2, 64);
                s += s3 + ((kb >= 0) ? s4 : 0.f);
            }
            s = act ? s * scale : -__builtin_inff();
            float mx = s;
#pragma unroll
            for (int m2 = 32; m2 >= 1; m2 >>= 1) mx = fmaxf(mx, __shfl_xor(mx, m2, 64));
            float e = act ? __expf(s - mx) : 0.f;
            float sum = e;
#pragma unroll
            for (int m2 = 32; m2 >= 1; m2 >>= 1) sum += __shfl_xor(sum, m2, 64);
            attacc += e / sum;
        }
        const float att = attacc * (1.f / 36.f);
        if (act) (side ? attP : attR)[(size_t)b * 36 + lane] = att;

        const int m = lane & 7;
        float w = __shfl(att, m, 64);
#pragma unroll
        for (int t = 0; t < 7; ++t) w += __shfl(att, 8 + c_POF[m][t], 64);
        if (lane < 8) (side ? wP : wR)[(size_t)b * 8 + m] = w;
    }
}

// ---- pooling + head: rb/pb bf16, rn/pn fp32. one block (128 thr) per b ----
__global__ __launch_bounds__(128) void pool2_kernel(
    const unsigned short* __restrict__ rb, const unsigned short* __restrict__ pb,
    const float* __restrict__ rn, const float* __restrict__ pn,
    const float* __restrict__ wR, const float* __restrict__ wP,
    const float* __restrict__ Wpred, const float* __restrict__ bpred,
    float* __restrict__ out)
{
    const int b = blockIdx.x;
    const int tid = threadIdx.x;           // d = tid*8 .. +8
    const int d0 = tid * 8;
    float a[8];
#pragma unroll
    for (int c = 0; c < 8; ++c) a[c] = 0.f;

#pragma unroll
    for (int m = 0; m < 8; ++m) {
        const float w = wR[b * 8 + m];
        const size_t base = ((size_t)m * 2048 + b) * 1024 + d0;
        short8 rv = *(const short8*)(rb + base);
        float4 n0 = *(const float4*)(rn + base);
        float4 n1 = *(const float4*)(rn + base + 4);
        a[0] += w * (bf2f((unsigned short)rv[0]) + n0.x);
        a[1] += w * (bf2f((unsigned short)rv[1]) + n0.y);
        a[2] += w * (bf2f((unsigned short)rv[2]) + n0.z);
        a[3] += w * (bf2f((unsigned short)rv[3]) + n0.w);
        a[4] += w * (bf2f((unsigned short)rv[4]) + n1.x);
        a[5] += w * (bf2f((unsigned short)rv[5]) + n1.y);
        a[6] += w * (bf2f((unsigned short)rv[6]) + n1.z);
        a[7] += w * (bf2f((unsigned short)rv[7]) + n1.w);
    }
#pragma unroll
    for (int m = 0; m < 8; ++m) {
        const float w = wP[b * 8 + m];
        const size_t base = ((size_t)m * 2048 + b) * 1024 + d0;
        short8 pv = *(const short8*)(pb + base);
        float4 n0 = *(const float4*)(pn + base);
        float4 n1 = *(const float4*)(pn + base + 4);
        a[0] -= w * (bf2f((unsigned short)pv[0]) + n0.x);
        a[1] -= w * (bf2f((unsigned short)pv[1]) + n0.y);
        a[2] -= w * (bf2f((unsigned short)pv[2]) + n0.z);
        a[3] -= w * (bf2f((unsigned short)pv[3]) + n0.w);
        a[4] -= w * (bf2f((unsigned short)pv[4]) + n1.x);
        a[5] -= w * (bf2f((unsigned short)pv[5]) + n1.y);
        a[6] -= w * (bf2f((unsigned short)pv[6]) + n1.z);
        a[7] -= w * (bf2f((unsigned short)pv[7]) + n1.w);
    }
    float o[4];
#pragma unroll
    for (int oo = 0; oo < 4; ++oo) {
        float4 w0 = *(const float4*)(Wpred + (size_t)oo * 1024 + d0);
        float4 w1 = *(const float4*)(Wpred + (size_t)oo * 1024 + d0 + 4);
        o[oo] = a[0]*w0.x + a[1]*w0.y + a[2]*w0.z + a[3]*w0.w
              + a[4]*w1.x + a[5]*w1.y + a[6]*w1.z + a[7]*w1.w;
    }
    const int lane = tid & 63, wave = tid >> 6;
#pragma unroll
    for (int oo = 0; oo < 4; ++oo)
#pragma unroll
        for (int m2 = 32; m2 >= 1; m2 >>= 1) o[oo] += __shfl_xor(o[oo], m2, 64);
    __shared__ float sm[2][4];
    if (lane == 0) { sm[wave][0] = o[0]; sm[wave][1] = o[1]; sm[wave][2] = o[2]; sm[wave][3] = o[3]; }
    __syncthreads();
    if (tid < 4) out[(size_t)b * 4 + tid] = sm[0][tid] + sm[1][tid] + bpred[tid];
}

// ===========================================================================
// FALLBACK PATH (exact R2 kernels) — used only if ws_size is too small
// ===========================================================================
template <typename BT>
__global__ __launch_bounds__(256) void gemm_bt_kernel(
    const float* __restrict__ A, const BT* __restrict__ Bt,
    unsigned short* __restrict__ C, int MA, int NB, int K)
{
    __shared__ unsigned short As[128 * 40];
    __shared__ unsigned short Bs[128 * 40];
    const int tid = threadIdx.x;
    const int m0 = blockIdx.y * 128;
    const int n0 = blockIdx.x * 128;
    const int srow = tid >> 1;
    const int sk   = (tid & 1) * 16;
    const int lane = tid & 63, wave = tid >> 6;
    const int wm = (wave & 1) * 64, wn = (wave >> 1) * 64;
    const int fm = lane & 15, quad = lane >> 4;
    f32x4 acc[4][4];
#pragma unroll
    for (int i = 0; i < 4; ++i)
#pragma unroll
        for (int j = 0; j < 4; ++j) acc[i][j] = (f32x4){0.f, 0.f, 0.f, 0.f};
    const float* aptr = A + (size_t)(m0 + srow) * K + sk;
    for (int k0 = 0; k0 < K; k0 += 32) {
        {
            const float4* s = (const float4*)(aptr + k0);
            float4 v0 = s[0], v1 = s[1], v2 = s[2], v3 = s[3];
            short8 p0, p1;
            p0[0]=(short)f2bf(v0.x); p0[1]=(short)f2bf(v0.y); p0[2]=(short)f2bf(v0.z); p0[3]=(short)f2bf(v0.w);
            p0[4]=(short)f2bf(v1.x); p0[5]=(short)f2bf(v1.y); p0[6]=(short)f2bf(v1.z); p0[7]=(short)f2bf(v1.w);
            p1[0]=(short)f2bf(v2.x); p1[1]=(short)f2bf(v2.y); p1[2]=(short)f2bf(v2.z); p1[3]=(short)f2bf(v2.w);
            p1[4]=(short)f2bf(v3.x); p1[5]=(short)f2bf(v3.y); p1[6]=(short)f2bf(v3.z); p1[7]=(short)f2bf(v3.w);
            *(short8*)&As[srow * 40 + sk] = p0;
            *(short8*)&As[srow * 40 + sk + 8] = p1;
        }
        if constexpr (std::is_same<BT, float>::value) {
            const float4* s = (const float4*)(Bt + (size_t)(n0 + srow) * K + k0 + sk);
            float4 v0 = s[0], v1 = s[1], v2 = s[2], v3 = s[3];
            short8 p0, p1;
            p0[0]=(short)f2bf(v0.x); p0[1]=(short)f2bf(v0.y); p0[2]=(short)f2bf(v0.z); p0[3]=(short)f2bf(v0.w);
            p0[4]=(short)f2bf(v1.x); p0[5]=(short)f2bf(v1.y); p0[6]=(short)f2bf(v1.z); p0[7]=(short)f2bf(v1.w);
            p1[0]=(short)f2bf(v2.x); p1[1]=(short)f2bf(v2.y); p1[2]=(short)f2bf(v2.z); p1[3]=(short)f2bf(v2.w);
            p1[4]=(short)f2bf(v3.x); p1[5]=(short)f2bf(v3.y); p1[6]=(short)f2bf(v3.z); p1[7]=(short)f2bf(v3.w);
            *(short8*)&Bs[srow * 40 + sk] = p0;
            *(short8*)&Bs[srow * 40 + sk + 8] = p1;
        } else {
            const short8* s = (const short8*)(Bt + (size_t)(n0 + srow) * K + k0 + sk);
            short8 u0 = s[0], u1 = s[1];
            *(short8*)&Bs[srow * 40 + sk] = u0;
            *(short8*)&Bs[srow * 40 + sk + 8] = u1;
        }
        __syncthreads();
        short8 af[4], bfr[4];
#pragma unroll
        for (int i = 0; i < 4; ++i)
            af[i] = *(const short8*)&As[(wm + i * 16 + fm) * 40 + quad * 8];
#pragma unroll
        for (int j = 0; j < 4; ++j)
            bfr[j] = *(const short8*)&Bs[(wn + j * 16 + fm) * 40 + quad * 8];
#pragma unroll
        for (int i = 0; i < 4; ++i)
#pragma unroll
            for (int j = 0; j < 4; ++j)
                acc[i][j] = __builtin_amdgcn_mfma_f32_16x16x32_bf16(af[i], bfr[j], acc[i][j], 0, 0, 0);
        __syncthreads();
    }
#pragma unroll
    for (int i = 0; i < 4; ++i)
#pragma unroll
        for (int j = 0; j < 4; ++j)
#pragma unroll
            for (int r = 0; r < 4; ++r) {
                const int row = m0 + wm + i * 16 + quad * 4 + r;
                const int col = n0 + wn + j * 16 + fm;
                C[(size_t)row * NB + col] = f2bf(acc[i][j][r]);
            }
}

__global__ __launch_bounds__(256) void gram_kernel(
    const unsigned short* __restrict__ T, const float* __restrict__ F,
    float* __restrict__ G, int Bsz)
{
    __shared__ float Tsh[8 * 1024];
    __shared__ float Fsh[8 * 1024];
    const int b = blockIdx.x;
    const int tid = threadIdx.x;
    {
        const int i = tid >> 5, seg = tid & 31;
        const ushort4* s4 = (const ushort4*)(T + ((size_t)i * Bsz + b) * 1024 + seg * 32);
        float* dst = Tsh + i * 1024 + seg * 32;
#pragma unroll
        for (int c = 0; c < 8; ++c) {
            ushort4 u = s4[c];
            dst[c*4+0] = bf2f(u.x); dst[c*4+1] = bf2f(u.y);
            dst[c*4+2] = bf2f(u.z); dst[c*4+3] = bf2f(u.w);
        }
        const float4* f4 = (const float4*)(F + ((size_t)i * Bsz + b) * 1024 + seg * 32);
        float4* fd = (float4*)(Fsh + i * 1024 + seg * 32);
#pragma unroll
        for (int c = 0; c < 8; ++c) fd[c] = f4[c];
    }
    __syncthreads();
    const int lane = tid & 63, wave = tid >> 6;
    const float4* T4 = (const float4*)Tsh;
    const float4* F4 = (const float4*)Fsh;
#pragma unroll
    for (int pp = 0; pp < 16; ++pp) {
        const int i = wave * 2 + (pp >> 3);
        const int j = pp & 7;
        float s = 0.f;
#pragma unroll
        for (int c = 0; c < 4; ++c) {
            float4 tv = T4[i * 256 + lane + 64 * c];
            float4 fv = F4[j * 256 + lane + 64 * c];
            s += tv.x*fv.x + tv.y*fv.y + tv.z*fv.z + tv.w*fv.w;
        }
#pragma unroll
        for (int m2 = 32; m2 >= 1; m2 >>= 1) s += __shfl_xor(s, m2, 64);
        if (lane == 0) G[((size_t)b << 6) + i * 8 + j] = s;
    }
}

__global__ __launch_bounds__(256) void pool_kernel(
    const float* __restrict__ r, const float* __restrict__ rn,
    const float* __restrict__ p, const float* __restrict__ pn,
    const float* __restrict__ wR, const float* __restrict__ wP,
    const float* __restrict__ Wpred, const float* __restrict__ bpred,
    float* __restrict__ out, int Bsz)
{
    const int b = blockIdx.x;
    const int tid = threadIdx.x;
    float ax = 0.f, ay = 0.f, az = 0.f, aw = 0.f;
#pragma unroll
    for (int m = 0; m < 8; ++m) {
        const float w = wR[b * 8 + m];
        const size_t off = ((size_t)m * Bsz + b) * 256 + tid;
        float4 rv = ((const float4*)r)[off];
        float4 rnv = ((const float4*)rn)[off];
        ax += w*(rv.x+rnv.x); ay += w*(rv.y+rnv.y); az += w*(rv.z+rnv.z); aw += w*(rv.w+rnv.w);
    }
#pragma unroll
    for (int m = 0; m < 8; ++m) {
        const float w = wP[b * 8 + m];
        const size_t off = ((size_t)m * Bsz + b) * 256 + tid;
        float4 pv = ((const float4*)p)[off];
        float4 pnv = ((const float4*)pn)[off];
        ax -= w*(pv.x+pnv.x); ay -= w*(pv.y+pnv.y); az -= w*(pv.z+pnv.z); aw -= w*(pv.w+pnv.w);
    }
    float o[4];
#pragma unroll
    for (int oo = 0; oo < 4; ++oo) {
        float4 w = ((const float4*)Wpred)[oo * 256 + tid];
        o[oo] = ax*w.x + ay*w.y + az*w.z + aw*w.w;
    }
    const int lane = tid & 63, wave = tid >> 6;
#pragma unroll
    for (int oo = 0; oo < 4; ++oo)
#pragma unroll
        for (int m2 = 32; m2 >= 1; m2 >>= 1) o[oo] += __shfl_xor(o[oo], m2, 64);
    __shared__ float sm[4][4];
    if (lane == 0) { sm[wave][0]=o[0]; sm[wave][1]=o[1]; sm[wave][2]=o[2]; sm[wave][3]=o[3]; }
    __syncthreads();
    if (tid < 4)
        out[(size_t)b * 4 + tid] = sm[0][tid] + sm[1][tid] + sm[2][tid] + sm[3][tid] + bpred[tid];
}

// ===========================================================================
extern "C" void kernel_launch(void* const* d_in, const int* in_sizes, int n_in,
                              void* d_out, int out_size, void* d_ws, size_t ws_size,
                              hipStream_t stream)
{
    const float* r     = (const float*)d_in[0];
    const float* p     = (const float*)d_in[1];
    const float* rn    = (const float*)d_in[2];
    const float* pn    = (const float*)d_in[3];
    const float* Wq    = (const float*)d_in[4];
    const float* Wk    = (const float*)d_in[5];
    const float* Wpred = (const float*)d_in[6];
    const float* bpred = (const float*)d_in[7];

    const int Bsz = 2048, MROW = 8 * 2048;
    char* ws = (char*)d_ws;

    float* out  = (float*)d_out;
    float* attR = out + (size_t)Bsz * 4;
    float* attP = attR + (size_t)Bsz * 36;

    const size_t MB = 1u << 20;
    const size_t REQ = 104 * MB;   // 3x32MB + 3x2MB + G/w

    if (ws_size >= REQ) {
        // ---------------- FAST PATH ----------------
        unsigned short* rb  = (unsigned short*)(ws);
        unsigned short* pb  = (unsigned short*)(ws + 32 * MB);
        unsigned short* T   = (unsigned short*)(ws + 64 * MB);
        unsigned short* Wqb = (unsigned short*)(ws + 96 * MB);
        unsigned short* Wkb = (unsigned short*)(ws + 98 * MB);
        unsigned short* Wct = (unsigned short*)(ws + 100 * MB);
        float* G1  = (float*)(ws + 102 * MB);
        float* G2  = G1 + (size_t)Bsz * 64;
        float* wRp = G2 + (size_t)Bsz * 64;
        float* wPp = wRp + (size_t)Bsz * 8;

        // 1. converts
        cvt_kernel<<<8192, 256, 0, stream>>>(r, rb, 2097152);
        cvt_kernel<<<8192, 256, 0, stream>>>(p, pb, 2097152);
        cvt_kernel<<<512, 256, 0, stream>>>(Wq, Wqb, 131072);
        cvt_kernel<<<512, 256, 0, stream>>>(Wk, Wkb, 131072);
        // 2. Wct[n,k] = sum_e Wk[n,e]*Wq[k,e]
        gemm_bf16_kernel<<<dim3(8, 8), 256, 0, stream>>>(Wkb, Wqb, Wct, 1024, 1024, 1024);
        // 3. T = p@Wc ; G1[b] = T_p[b] r[b]^T
        gemm_bf16_kernel<<<dim3(128, 8), 256, 0, stream>>>(pb, Wct, T, MROW, 1024, 1024);
        gram_mfma_kernel<<<256, 256, 0, stream>>>(T, rb, G1);
        // 4. T = r@Wc ; G2[b] = T_r[b] p[b]^T
        gemm_bf16_kernel<<<dim3(128, 8), 256, 0, stream>>>(rb, Wct, T, MROW, 1024, 1024);
        gram_mfma_kernel<<<256, 256, 0, stream>>>(T, pb, G2);
        // 5. softmax + pooled weights
        att_kernel<<<Bsz / 4, 256, 0, stream>>>(G1, G2, attR, attP, wRp, wPp, Bsz);
        // 6. pooling + head
        pool2_kernel<<<Bsz, 128, 0, stream>>>(rb, pb, rn, pn, wRp, wPp, Wpred, bpred, out);
    } else {
        // ---------------- FALLBACK (R2) ----------------
        unsigned short* Wct = (unsigned short*)ws;
        unsigned short* T   = (unsigned short*)(ws + (size_t)(2 << 20));
        float* G1  = (float*)(ws + (size_t)(34 << 20));
        float* G2  = G1 + (size_t)Bsz * 64;
        float* wRp = G2 + (size_t)Bsz * 64;
        float* wPp = wRp + (size_t)Bsz * 8;

        gemm_bt_kernel<float><<<dim3(8, 8), 256, 0, stream>>>(Wk, Wq, Wct, 1024, 1024, 1024);
        gemm_bt_kernel<unsigned short><<<dim3(8, 128), 256, 0, stream>>>(p, Wct, T, MROW, 1024, 1024);
        gram_kernel<<<Bsz, 256, 0, stream>>>(T, r, G1, Bsz);
        gemm_bt_kernel<unsigned short><<<dim3(8, 128), 256, 0, stream>>>(r, Wct, T, MROW, 1024, 1024);
        gram_kernel<<<Bsz, 256, 0, stream>>>(T, p, G2, Bsz);
        att_kernel<<<Bsz / 4, 256, 0, stream>>>(G1, G2, attR, attP, wRp, wPp, Bsz);
        pool_kernel<<<Bsz, 256, 0, stream>>>(r, rn, p, pn, wRp, wPp, Wpred, bpred, out, Bsz);
    }
}

// Round 4
// 443.716 us; speedup vs baseline: 1.3360x; 1.0476x over previous
//
#include <hip/hip_runtime.h>
#include <hip/hip_bf16.h>
#include <type_traits>

typedef __attribute__((ext_vector_type(8))) short short8;
typedef __attribute__((ext_vector_type(4))) float f32x4;

__device__ __forceinline__ unsigned short f2bf(float f) {
    union { float f; unsigned int u; } v; v.f = f;
    unsigned int r = v.u + 0x7FFFu + ((v.u >> 16) & 1u);
    return (unsigned short)(r >> 16);
}
__device__ __forceinline__ float bf2f(unsigned short u) {
    union { unsigned int u; float f; } v; v.u = ((unsigned int)u) << 16;
    return v.f;
}

// async global->LDS, 16B per lane (m97 recipe). LDS dest is lane-linear.
__device__ __forceinline__ void gl_lds16(const unsigned short* g, unsigned short* l) {
    __builtin_amdgcn_global_load_lds(
        (const __attribute__((address_space(1))) void*)g,
        (__attribute__((address_space(3))) void*)l, 16, 0, 0);
}

// ===========================================================================
// FAST PATH
// ===========================================================================

// ---- fused fp32 -> bf16 convert of all four tensors, 8 elems/thread ------
// segments (in 8-elem groups): r 2097152 | p 2097152 | Wq 131072 | Wk 131072
__global__ __launch_bounds__(256) void cvt_all_kernel(
    const float* __restrict__ r, const float* __restrict__ p,
    const float* __restrict__ wq, const float* __restrict__ wk,
    unsigned short* __restrict__ rb, unsigned short* __restrict__ pb,
    unsigned short* __restrict__ wqb, unsigned short* __restrict__ wkb)
{
    int idx = blockIdx.x * 256 + threadIdx.x;
    const float* src; unsigned short* dst; int off;
    if (idx < 2097152)      { src = r;  dst = rb;  off = idx; }
    else if (idx < 4194304) { src = p;  dst = pb;  off = idx - 2097152; }
    else if (idx < 4325376) { src = wq; dst = wqb; off = idx - 4194304; }
    else                    { src = wk; dst = wkb; off = idx - 4325376; }
    const float4* s = (const float4*)src + (size_t)off * 2;
    float4 v0 = s[0], v1 = s[1];
    short8 o;
    o[0] = (short)f2bf(v0.x); o[1] = (short)f2bf(v0.y);
    o[2] = (short)f2bf(v0.z); o[3] = (short)f2bf(v0.w);
    o[4] = (short)f2bf(v1.x); o[5] = (short)f2bf(v1.y);
    o[6] = (short)f2bf(v1.z); o[7] = (short)f2bf(v1.w);
    ((short8*)dst)[off] = o;
}

// ---- bf16 GEMM: C[m,n] = sum_k A[m,k]*Bt[n,k] ----------------------------
// 128x128 tile, BK=64 staged as two independent 128x32 half-tiles (keeps the
// R3 64B-row bank layout) -> half the barrier drains of BK=32.
// grid.x = m-tile (XCD swizzle: 8 n-blocks of a stripe share an XCD).
__global__ __launch_bounds__(256) void gemm_bf16_kernel(
    const unsigned short* __restrict__ A, const unsigned short* __restrict__ Bt,
    unsigned short* __restrict__ C, int NB, int K)
{
    __shared__ unsigned short As[2][128 * 32];   // 2 x 8 KB
    __shared__ unsigned short Bs[2][128 * 32];

    const int tid = threadIdx.x;
    const int m0 = blockIdx.x * 128;
    const int n0 = blockIdx.y * 128;

    const int lane = tid & 63, wave = tid >> 6;
    const int wm = (wave & 1) * 64, wn = (wave >> 1) * 64;
    const int fm = lane & 15, quad = lane >> 4;

    // per-half staging map: slot s = e*256+tid -> row=s>>2 (e*64+tid>>2),
    // colgroup=(s&3)*8; LDS offset s*8 == row*32 + col.
    const int srow = tid >> 2;
    const int scol = (tid & 3) * 8;

    f32x4 acc[4][4];
#pragma unroll
    for (int i = 0; i < 4; ++i)
#pragma unroll
        for (int j = 0; j < 4; ++j) acc[i][j] = (f32x4){0.f, 0.f, 0.f, 0.f};

    const unsigned short* a0 = A + (size_t)(m0 + srow) * K + scol;
    const unsigned short* b0 = Bt + (size_t)(n0 + srow) * K + scol;
    const size_t rstep = (size_t)64 * K;

    for (int k0 = 0; k0 < K; k0 += 64) {
#pragma unroll
        for (int h = 0; h < 2; ++h) {
            const int gc = k0 + h * 32;
            gl_lds16(a0 + gc,         As[h] + (size_t)tid * 8);
            gl_lds16(a0 + gc + rstep, As[h] + (size_t)(256 + tid) * 8);
            gl_lds16(b0 + gc,         Bs[h] + (size_t)tid * 8);
            gl_lds16(b0 + gc + rstep, Bs[h] + (size_t)(256 + tid) * 8);
        }
        __syncthreads();          // drains vmcnt (compiler-emitted full waitcnt)

#pragma unroll
        for (int h = 0; h < 2; ++h) {
            short8 af[4], bfr[4];
#pragma unroll
            for (int i = 0; i < 4; ++i)
                af[i] = *(const short8*)&As[h][(wm + i * 16 + fm) * 32 + quad * 8];
#pragma unroll
            for (int j = 0; j < 4; ++j)
                bfr[j] = *(const short8*)&Bs[h][(wn + j * 16 + fm) * 32 + quad * 8];
#pragma unroll
            for (int i = 0; i < 4; ++i)
#pragma unroll
                for (int j = 0; j < 4; ++j)
                    acc[i][j] = __builtin_amdgcn_mfma_f32_16x16x32_bf16(
                        af[i], bfr[j], acc[i][j], 0, 0, 0);
        }
        __syncthreads();
    }

    // D layout: col=lane&15, row=quad*4+reg [m89]
#pragma unroll
    for (int i = 0; i < 4; ++i)
#pragma unroll
        for (int j = 0; j < 4; ++j)
#pragma unroll
            for (int r = 0; r < 4; ++r) {
                const int row = m0 + wm + i * 16 + quad * 4 + r;
                const int col = n0 + wn + j * 16 + fm;
                C[(size_t)row * NB + col] = f2bf(acc[i][j][r]);
            }
}

// ---- MFMA gram: G[b,i,j] = sum_d T[i*2048+b,d] * F[j*2048+b,d] -----------
__global__ __launch_bounds__(256) void gram_mfma_kernel(
    const unsigned short* __restrict__ T, const unsigned short* __restrict__ F,
    float* __restrict__ G)
{
    const int lane = threadIdx.x & 63, wave = threadIdx.x >> 6;
    const int b = blockIdx.x * 8 + wave * 2;          // batches b, b+1
    const int fm = lane & 15, quad = lane >> 4;

    const size_t row = (size_t)(fm & 7) * 2048 + (size_t)b + (fm >> 3);
    const unsigned short* tp = T + row * 1024 + quad * 8;
    const unsigned short* fp = F + row * 1024 + quad * 8;

    f32x4 acc = (f32x4){0.f, 0.f, 0.f, 0.f};
#pragma unroll 4
    for (int k0 = 0; k0 < 1024; k0 += 32) {
        short8 a = *(const short8*)(tp + k0);
        short8 bb = *(const short8*)(fp + k0);
        acc = __builtin_amdgcn_mfma_f32_16x16x32_bf16(a, bb, acc, 0, 0, 0);
    }
    if ((quad >> 1) == (fm >> 3)) {
        const int bb_ = b + (fm >> 3);
        const int j = fm & 7;
#pragma unroll
        for (int r = 0; r < 4; ++r) {
            const int m = ((quad * 4 + r) & 7);
            G[(size_t)bb_ * 64 + m * 8 + j] = acc[r];
        }
    }
}

// ---- softmax / att maps / pooled weights ---------------------------------
__device__ __constant__ int c_PI[28] = {0,0,0,0,0,0,0, 1,1,1,1,1,1, 2,2,2,2,2, 3,3,3,3, 4,4,4, 5,5, 6};
__device__ __constant__ int c_PJ[28] = {1,2,3,4,5,6,7, 2,3,4,5,6,7, 3,4,5,6,7, 4,5,6,7, 5,6,7, 6,7, 7};
__device__ __constant__ int c_POF[8][7] = {
    {0,1,2,3,4,5,6},      {0,7,8,9,10,11,12},   {1,7,13,14,15,16,17}, {2,8,13,18,19,20,21},
    {3,9,14,18,22,23,24}, {4,10,15,19,22,25,26},{5,11,16,20,23,25,27},{6,12,17,21,24,26,27}};

__global__ __launch_bounds__(256) void att_kernel(
    const float* __restrict__ G1, const float* __restrict__ G2,
    float* __restrict__ attR, float* __restrict__ attP,
    float* __restrict__ wR, float* __restrict__ wP, int Bsz)
{
    const int lane = threadIdx.x & 63;
    const int wave = threadIdx.x >> 6;
    const int b = blockIdx.x * 4 + wave;

    int ka, kb;
    if (lane < 8)       { ka = lane;            kb = -1; }
    else if (lane < 36) { ka = c_PI[lane - 8];  kb = c_PJ[lane - 8]; }
    else                { ka = 0;               kb = -1; }
    const bool act = lane < 36;
    const float scale = 0.03125f;

    for (int side = 0; side < 2; ++side) {
        const float* G = side ? G2 : G1;
        float g = G[((size_t)b << 6) + lane];
        float attacc = 0.f;
        for (int q = 0; q < 36; ++q) {
            int qa, qb;
            if (q < 8) { qa = q;           qb = -1; }
            else       { qa = c_PI[q - 8]; qb = c_PJ[q - 8]; }
            const int kb2 = (kb < 0) ? ka : kb;
            float s  = __shfl(g, qa * 8 + ka, 64);
            float s2 = __shfl(g, qa * 8 + kb2, 64);
            s += (kb >= 0) ? s2 : 0.f;
            if (qb >= 0) {
                float s3 = __shfl(g, qb * 8 + ka, 64);
                float s4 = __shfl(g, qb * 8 + kb2, 64);
                s += s3 + ((kb >= 0) ? s4 : 0.f);
            }
            s = act ? s * scale : -__builtin_inff();
            float mx = s;
#pragma unroll
            for (int m2 = 32; m2 >= 1; m2 >>= 1) mx = fmaxf(mx, __shfl_xor(mx, m2, 64));
            float e = act ? __expf(s - mx) : 0.f;
            float sum = e;
#pragma unroll
            for (int m2 = 32; m2 >= 1; m2 >>= 1) sum += __shfl_xor(sum, m2, 64);
            attacc += e / sum;
        }
        const float att = attacc * (1.f / 36.f);
        if (act) (side ? attP : attR)[(size_t)b * 36 + lane] = att;

        const int m = lane & 7;
        float w = __shfl(att, m, 64);
#pragma unroll
        for (int t = 0; t < 7; ++t) w += __shfl(att, 8 + c_POF[m][t], 64);
        if (lane < 8) (side ? wP : wR)[(size_t)b * 8 + m] = w;
    }
}

// ---- pooling + head: rb/pb bf16, rn/pn fp32. one block (128 thr) per b ----
__global__ __launch_bounds__(128) void pool2_kernel(
    const unsigned short* __restrict__ rb, const unsigned short* __restrict__ pb,
    const float* __restrict__ rn, const float* __restrict__ pn,
    const float* __restrict__ wR, const float* __restrict__ wP,
    const float* __restrict__ Wpred, const float* __restrict__ bpred,
    float* __restrict__ out)
{
    const int b = blockIdx.x;
    const int tid = threadIdx.x;           // d = tid*8 .. +8
    const int d0 = tid * 8;
    float a[8];
#pragma unroll
    for (int c = 0; c < 8; ++c) a[c] = 0.f;

#pragma unroll
    for (int m = 0; m < 8; ++m) {
        const float w = wR[b * 8 + m];
        const size_t base = ((size_t)m * 2048 + b) * 1024 + d0;
        short8 rv = *(const short8*)(rb + base);
        float4 n0 = *(const float4*)(rn + base);
        float4 n1 = *(const float4*)(rn + base + 4);
        a[0] += w * (bf2f((unsigned short)rv[0]) + n0.x);
        a[1] += w * (bf2f((unsigned short)rv[1]) + n0.y);
        a[2] += w * (bf2f((unsigned short)rv[2]) + n0.z);
        a[3] += w * (bf2f((unsigned short)rv[3]) + n0.w);
        a[4] += w * (bf2f((unsigned short)rv[4]) + n1.x);
        a[5] += w * (bf2f((unsigned short)rv[5]) + n1.y);
        a[6] += w * (bf2f((unsigned short)rv[6]) + n1.z);
        a[7] += w * (bf2f((unsigned short)rv[7]) + n1.w);
    }
#pragma unroll
    for (int m = 0; m < 8; ++m) {
        const float w = wP[b * 8 + m];
        const size_t base = ((size_t)m * 2048 + b) * 1024 + d0;
        short8 pv = *(const short8*)(pb + base);
        float4 n0 = *(const float4*)(pn + base);
        float4 n1 = *(const float4*)(pn + base + 4);
        a[0] -= w * (bf2f((unsigned short)pv[0]) + n0.x);
        a[1] -= w * (bf2f((unsigned short)pv[1]) + n0.y);
        a[2] -= w * (bf2f((unsigned short)pv[2]) + n0.z);
        a[3] -= w * (bf2f((unsigned short)pv[3]) + n0.w);
        a[4] -= w * (bf2f((unsigned short)pv[4]) + n1.x);
        a[5] -= w * (bf2f((unsigned short)pv[5]) + n1.y);
        a[6] -= w * (bf2f((unsigned short)pv[6]) + n1.z);
        a[7] -= w * (bf2f((unsigned short)pv[7]) + n1.w);
    }
    float o[4];
#pragma unroll
    for (int oo = 0; oo < 4; ++oo) {
        float4 w0 = *(const float4*)(Wpred + (size_t)oo * 1024 + d0);
        float4 w1 = *(const float4*)(Wpred + (size_t)oo * 1024 + d0 + 4);
        o[oo] = a[0]*w0.x + a[1]*w0.y + a[2]*w0.z + a[3]*w0.w
              + a[4]*w1.x + a[5]*w1.y + a[6]*w1.z + a[7]*w1.w;
    }
    const int lane = tid & 63, wave = tid >> 6;
#pragma unroll
    for (int oo = 0; oo < 4; ++oo)
#pragma unroll
        for (int m2 = 32; m2 >= 1; m2 >>= 1) o[oo] += __shfl_xor(o[oo], m2, 64);
    __shared__ float sm[2][4];
    if (lane == 0) { sm[wave][0] = o[0]; sm[wave][1] = o[1]; sm[wave][2] = o[2]; sm[wave][3] = o[3]; }
    __syncthreads();
    if (tid < 4) out[(size_t)b * 4 + tid] = sm[0][tid] + sm[1][tid] + bpred[tid];
}

// ===========================================================================
// FALLBACK PATH (R2 kernels) — used only if ws_size is too small
// ===========================================================================
template <typename BT>
__global__ __launch_bounds__(256) void gemm_bt_kernel(
    const float* __restrict__ A, const BT* __restrict__ Bt,
    unsigned short* __restrict__ C, int MA, int NB, int K)
{
    __shared__ unsigned short As[128 * 40];
    __shared__ unsigned short Bs[128 * 40];
    const int tid = threadIdx.x;
    const int m0 = blockIdx.y * 128;
    const int n0 = blockIdx.x * 128;
    const int srow = tid >> 1;
    const int sk   = (tid & 1) * 16;
    const int lane = tid & 63, wave = tid >> 6;
    const int wm = (wave & 1) * 64, wn = (wave >> 1) * 64;
    const int fm = lane & 15, quad = lane >> 4;
    f32x4 acc[4][4];
#pragma unroll
    for (int i = 0; i < 4; ++i)
#pragma unroll
        for (int j = 0; j < 4; ++j) acc[i][j] = (f32x4){0.f, 0.f, 0.f, 0.f};
    const float* aptr = A + (size_t)(m0 + srow) * K + sk;
    for (int k0 = 0; k0 < K; k0 += 32) {
        {
            const float4* s = (const float4*)(aptr + k0);
            float4 v0 = s[0], v1 = s[1], v2 = s[2], v3 = s[3];
            short8 p0, p1;
            p0[0]=(short)f2bf(v0.x); p0[1]=(short)f2bf(v0.y); p0[2]=(short)f2bf(v0.z); p0[3]=(short)f2bf(v0.w);
            p0[4]=(short)f2bf(v1.x); p0[5]=(short)f2bf(v1.y); p0[6]=(short)f2bf(v1.z); p0[7]=(short)f2bf(v1.w);
            p1[0]=(short)f2bf(v2.x); p1[1]=(short)f2bf(v2.y); p1[2]=(short)f2bf(v2.z); p1[3]=(short)f2bf(v2.w);
            p1[4]=(short)f2bf(v3.x); p1[5]=(short)f2bf(v3.y); p1[6]=(short)f2bf(v3.z); p1[7]=(short)f2bf(v3.w);
            *(short8*)&As[srow * 40 + sk] = p0;
            *(short8*)&As[srow * 40 + sk + 8] = p1;
        }
        if constexpr (std::is_same<BT, float>::value) {
            const float4* s = (const float4*)(Bt + (size_t)(n0 + srow) * K + k0 + sk);
            float4 v0 = s[0], v1 = s[1], v2 = s[2], v3 = s[3];
            short8 p0, p1;
            p0[0]=(short)f2bf(v0.x); p0[1]=(short)f2bf(v0.y); p0[2]=(short)f2bf(v0.z); p0[3]=(short)f2bf(v0.w);
            p0[4]=(short)f2bf(v1.x); p0[5]=(short)f2bf(v1.y); p0[6]=(short)f2bf(v1.z); p0[7]=(short)f2bf(v1.w);
            p1[0]=(short)f2bf(v2.x); p1[1]=(short)f2bf(v2.y); p1[2]=(short)f2bf(v2.z); p1[3]=(short)f2bf(v2.w);
            p1[4]=(short)f2bf(v3.x); p1[5]=(short)f2bf(v3.y); p1[6]=(short)f2bf(v3.z); p1[7]=(short)f2bf(v3.w);
            *(short8*)&Bs[srow * 40 + sk] = p0;
            *(short8*)&Bs[srow * 40 + sk + 8] = p1;
        } else {
            const short8* s = (const short8*)(Bt + (size_t)(n0 + srow) * K + k0 + sk);
            short8 u0 = s[0], u1 = s[1];
            *(short8*)&Bs[srow * 40 + sk] = u0;
            *(short8*)&Bs[srow * 40 + sk + 8] = u1;
        }
        __syncthreads();
        short8 af[4], bfr[4];
#pragma unroll
        for (int i = 0; i < 4; ++i)
            af[i] = *(const short8*)&As[(wm + i * 16 + fm) * 40 + quad * 8];
#pragma unroll
        for (int j = 0; j < 4; ++j)
            bfr[j] = *(const short8*)&Bs[(wn + j * 16 + fm) * 40 + quad * 8];
#pragma unroll
        for (int i = 0; i < 4; ++i)
#pragma unroll
            for (int j = 0; j < 4; ++j)
                acc[i][j] = __builtin_amdgcn_mfma_f32_16x16x32_bf16(af[i], bfr[j], acc[i][j], 0, 0, 0);
        __syncthreads();
    }
#pragma unroll
    for (int i = 0; i < 4; ++i)
#pragma unroll
        for (int j = 0; j < 4; ++j)
#pragma unroll
            for (int r = 0; r < 4; ++r) {
                const int row = m0 + wm + i * 16 + quad * 4 + r;
                const int col = n0 + wn + j * 16 + fm;
                C[(size_t)row * NB + col] = f2bf(acc[i][j][r]);
            }
}

__global__ __launch_bounds__(256) void gram_kernel(
    const unsigned short* __restrict__ T, const float* __restrict__ F,
    float* __restrict__ G, int Bsz)
{
    __shared__ float Tsh[8 * 1024];
    __shared__ float Fsh[8 * 1024];
    const int b = blockIdx.x;
    const int tid = threadIdx.x;
    {
        const int i = tid >> 5, seg = tid & 31;
        const ushort4* s4 = (const ushort4*)(T + ((size_t)i * Bsz + b) * 1024 + seg * 32);
        float* dst = Tsh + i * 1024 + seg * 32;
#pragma unroll
        for (int c = 0; c < 8; ++c) {
            ushort4 u = s4[c];
            dst[c*4+0] = bf2f(u.x); dst[c*4+1] = bf2f(u.y);
            dst[c*4+2] = bf2f(u.z); dst[c*4+3] = bf2f(u.w);
        }
        const float4* f4 = (const float4*)(F + ((size_t)i * Bsz + b) * 1024 + seg * 32);
        float4* fd = (float4*)(Fsh + i * 1024 + seg * 32);
#pragma unroll
        for (int c = 0; c < 8; ++c) fd[c] = f4[c];
    }
    __syncthreads();
    const int lane = tid & 63, wave = tid >> 6;
    const float4* T4 = (const float4*)Tsh;
    const float4* F4 = (const float4*)Fsh;
#pragma unroll
    for (int pp = 0; pp < 16; ++pp) {
        const int i = wave * 2 + (pp >> 3);
        const int j = pp & 7;
        float s = 0.f;
#pragma unroll
        for (int c = 0; c < 4; ++c) {
            float4 tv = T4[i * 256 + lane + 64 * c];
            float4 fv = F4[j * 256 + lane + 64 * c];
            s += tv.x*fv.x + tv.y*fv.y + tv.z*fv.z + tv.w*fv.w;
        }
#pragma unroll
        for (int m2 = 32; m2 >= 1; m2 >>= 1) s += __shfl_xor(s, m2, 64);
        if (lane == 0) G[((size_t)b << 6) + i * 8 + j] = s;
    }
}

__global__ __launch_bounds__(256) void pool_kernel(
    const float* __restrict__ r, const float* __restrict__ rn,
    const float* __restrict__ p, const float* __restrict__ pn,
    const float* __restrict__ wR, const float* __restrict__ wP,
    const float* __restrict__ Wpred, const float* __restrict__ bpred,
    float* __restrict__ out, int Bsz)
{
    const int b = blockIdx.x;
    const int tid = threadIdx.x;
    float ax = 0.f, ay = 0.f, az = 0.f, aw = 0.f;
#pragma unroll
    for (int m = 0; m < 8; ++m) {
        const float w = wR[b * 8 + m];
        const size_t off = ((size_t)m * Bsz + b) * 256 + tid;
        float4 rv = ((const float4*)r)[off];
        float4 rnv = ((const float4*)rn)[off];
        ax += w*(rv.x+rnv.x); ay += w*(rv.y+rnv.y); az += w*(rv.z+rnv.z); aw += w*(rv.w+rnv.w);
    }
#pragma unroll
    for (int m = 0; m < 8; ++m) {
        const float w = wP[b * 8 + m];
        const size_t off = ((size_t)m * Bsz + b) * 256 + tid;
        float4 pv = ((const float4*)p)[off];
        float4 pnv = ((const float4*)pn)[off];
        ax -= w*(pv.x+pnv.x); ay -= w*(pv.y+pnv.y); az -= w*(pv.z+pnv.z); aw -= w*(pv.w+pnv.w);
    }
    float o[4];
#pragma unroll
    for (int oo = 0; oo < 4; ++oo) {
        float4 w = ((const float4*)Wpred)[oo * 256 + tid];
        o[oo] = ax*w.x + ay*w.y + az*w.z + aw*w.w;
    }
    const int lane = tid & 63, wave = tid >> 6;
#pragma unroll
    for (int oo = 0; oo < 4; ++oo)
#pragma unroll
        for (int m2 = 32; m2 >= 1; m2 >>= 1) o[oo] += __shfl_xor(o[oo], m2, 64);
    __shared__ float sm[4][4];
    if (lane == 0) { sm[wave][0]=o[0]; sm[wave][1]=o[1]; sm[wave][2]=o[2]; sm[wave][3]=o[3]; }
    __syncthreads();
    if (tid < 4)
        out[(size_t)b * 4 + tid] = sm[0][tid] + sm[1][tid] + sm[2][tid] + sm[3][tid] + bpred[tid];
}

// ===========================================================================
extern "C" void kernel_launch(void* const* d_in, const int* in_sizes, int n_in,
                              void* d_out, int out_size, void* d_ws, size_t ws_size,
                              hipStream_t stream)
{
    const float* r     = (const float*)d_in[0];
    const float* p     = (const float*)d_in[1];
    const float* rn    = (const float*)d_in[2];
    const float* pn    = (const float*)d_in[3];
    const float* Wq    = (const float*)d_in[4];
    const float* Wk    = (const float*)d_in[5];
    const float* Wpred = (const float*)d_in[6];
    const float* bpred = (const float*)d_in[7];

    const int Bsz = 2048, MROW = 8 * 2048;
    char* ws = (char*)d_ws;

    float* out  = (float*)d_out;
    float* attR = out + (size_t)Bsz * 4;
    float* attP = attR + (size_t)Bsz * 36;

    const size_t MB = 1u << 20;
    const size_t REQ = 104 * MB;

    if (ws_size >= REQ) {
        // ---------------- FAST PATH ----------------
        unsigned short* rb  = (unsigned short*)(ws);
        unsigned short* pb  = (unsigned short*)(ws + 32 * MB);
        unsigned short* T   = (unsigned short*)(ws + 64 * MB);
        unsigned short* Wqb = (unsigned short*)(ws + 96 * MB);
        unsigned short* Wkb = (unsigned short*)(ws + 98 * MB);
        unsigned short* Wct = (unsigned short*)(ws + 100 * MB);
        float* G1  = (float*)(ws + 102 * MB);
        float* G2  = G1 + (size_t)Bsz * 64;
        float* wRp = G2 + (size_t)Bsz * 64;
        float* wPp = wRp + (size_t)Bsz * 8;

        // 1. all converts in one launch (4456448 groups / 256 = 17408 blocks)
        cvt_all_kernel<<<17408, 256, 0, stream>>>(r, p, Wq, Wk, rb, pb, Wqb, Wkb);
        // 2. Wct[n,k] = sum_e Wk[n,e]*Wq[k,e]
        gemm_bf16_kernel<<<dim3(8, 8), 256, 0, stream>>>(Wkb, Wqb, Wct, 1024, 1024);
        // 3. T = p@Wc ; G1[b] = T_p[b] r[b]^T
        gemm_bf16_kernel<<<dim3(128, 8), 256, 0, stream>>>(pb, Wct, T, 1024, 1024);
        gram_mfma_kernel<<<256, 256, 0, stream>>>(T, rb, G1);
        // 4. T = r@Wc ; G2[b] = T_r[b] p[b]^T
        gemm_bf16_kernel<<<dim3(128, 8), 256, 0, stream>>>(rb, Wct, T, 1024, 1024);
        gram_mfma_kernel<<<256, 256, 0, stream>>>(T, pb, G2);
        // 5. softmax + pooled weights
        att_kernel<<<Bsz / 4, 256, 0, stream>>>(G1, G2, attR, attP, wRp, wPp, Bsz);
        // 6. pooling + head
        pool2_kernel<<<Bsz, 128, 0, stream>>>(rb, pb, rn, pn, wRp, wPp, Wpred, bpred, out);
    } else {
        // ---------------- FALLBACK (R2) ----------------
        unsigned short* Wct = (unsigned short*)ws;
        unsigned short* T   = (unsigned short*)(ws + (size_t)(2 << 20));
        float* G1  = (float*)(ws + (size_t)(34 << 20));
        float* G2  = G1 + (size_t)Bsz * 64;
        float* wRp = G2 + (size_t)Bsz * 64;
        float* wPp = wRp + (size_t)Bsz * 8;

        gemm_bt_kernel<float><<<dim3(8, 8), 256, 0, stream>>>(Wk, Wq, Wct, 1024, 1024, 1024);
        gemm_bt_kernel<unsigned short><<<dim3(8, 128), 256, 0, stream>>>(p, Wct, T, MROW, 1024, 1024);
        gram_kernel<<<Bsz, 256, 0, stream>>>(T, r, G1, Bsz);
        gemm_bt_kernel<unsigned short><<<dim3(8, 128), 256, 0, stream>>>(r, Wct, T, MROW, 1024, 1024);
        gram_kernel<<<Bsz, 256, 0, stream>>>(T, p, G2, Bsz);
        att_kernel<<<Bsz / 4, 256, 0, stream>>>(G1, G2, attR, attP, wRp, wPp, Bsz);
        pool_kernel<<<Bsz, 256, 0, stream>>>(r, rn, p, pn, wRp, wPp, Wpred, bpred, out, Bsz);
    }
}